// Round 6
// baseline (105.987 us; speedup 1.0000x reference)
//
#include <hip/hip_runtime.h>
#include <math.h>

// QuantumPolicy: MLP(6->64->6) -> 6-qubit RY/CNOT circuit (4 layers) -> Z exp
// -> softmax policy head (4) + value head (1).
//
// Pipeline:
//   1) mlp_kernel (B threads): xp = relu(relu(x@W1^T+b1)@W2^T+b2), then
//      (cos,sin)(xp/2) per qubit stored to ws (12 floats/sample). Block 0 also
//      writes the per-layer rotation-constant table.
//   2) qpolicy_kernel (2B threads): LANE-SPLIT circuit. Qubit 0 = lane parity
//      (DPP quad pairs), qubits 1..4 = register index bits (b3..b0), qubit 5 =
//      v2 component; 16 x float2 per lane, 8 waves/SIMD.
//
// ROUND-6: round-4-verified circuit structure (the round-5 Pauli-frame CNOT
// elimination was algebraically UNSOUND: pushing CNOT(5,0) through frame flags
// on q1..q4 generates CX(5,i) junk -- CX(5,0)CX(0,i) = CX(0,i)CX(5,i)CX(5,0)
// -- which the fused step didn't implement). Kept from round 5 only the
// independently-verified pieces:
//  - sincos hoisted into mlp_kernel (6 fewer transcendental pairs in the
//    2B-thread kernel; paid once per sample in the B-thread kernel);
//  - fused CNOT(5,0)+RY(q0) in KA/KB form (identical algebra to round 4's
//    verified step, fewer marshal movs): st' = KA*st + KB*(dx,dy),
//    KA=(c,ssg), KB=(ssg,c), ssg = podd ? s : -s;
//  - RY(q5) as packed direct rotation: st' = c*st + (-s,s)*swap(st)
//    (exact: (c x - s y, s x + c y)); 32 pk ops vs 48 scalar fma;
//  - packed (v2) embedding + measurement trees, horizontalize once;
//  - layer-0 CNOT(0,1) folded into the embedding tree (round-4-verified);
//    l>0 instances stay as 32 full-rate cndmask.
//
// ws layout (floats): [0..63] layer consts (16/layer:
//   c0,s0, nt1,s1, nt2,s2, nt3,s3, nt4,s4, c5,s5, pad),
//   [256..] per-sample (c,s) pairs, 12 floats/sample (~12.6 MB).

#define NQ 6
#define NL 4
#define NA 4
#define PD 64

typedef float v2 __attribute__((ext_vector_type(2)));

static __device__ __forceinline__ v2 mk2(float a, float b) { v2 r; r.x = a; r.y = b; return r; }
static __device__ __forceinline__ v2 pkfma(v2 a, v2 b, v2 c) { return __builtin_elementwise_fma(a, b, c); }

// Swap with DPP-quad neighbor (lane ^ 1). Full-rate VALU, exec all-on.
static __device__ __forceinline__ float dppx1(float v) {
    int i = __builtin_bit_cast(int, v);
    i = __builtin_amdgcn_mov_dpp(i, 0xB1, 0xF, 0xF, true); // quad_perm [1,0,3,2]
    return __builtin_bit_cast(float, i);
}

// ---- kernel 1: per-sample MLP + angle sincos (+ layer consts on block 0).
__global__ __launch_bounds__(256) void mlp_kernel(
    const float* __restrict__ x,
    const float* __restrict__ W1,
    const float* __restrict__ b1,
    const float* __restrict__ W2,
    const float* __restrict__ b2,
    const float* __restrict__ qw,
    float* __restrict__ ws,
    int B)
{
    const int s = blockIdx.x * blockDim.x + threadIdx.x;

    if (blockIdx.x == 0 && threadIdx.x < NL * NQ) {
        const int l = threadIdx.x / NQ, i = threadIdx.x % NQ;
        const float hh0 = 0.5f * qw[l * NQ + i];
        float* dst = ws + l * 16;
        if (i == 0) {                      // q0: direct rotation (c,s)
            dst[0] = cosf(hh0);
            dst[1] = sinf(hh0);
        } else if (i == 5) {               // q5: direct rotation (c,s)
            dst[10] = cosf(hh0);
            dst[11] = sinf(hh0);
        } else {                           // q1..q4: shear consts, range-reduced
            const float hh = (hh0 > 1.5707963f) ? (hh0 - 3.14159265358979f) : hh0;
            const float sh = sinf(hh), ch = cosf(hh);
            dst[2 * i]     = -sh / (1.0f + ch);   // -tan(h/2), |t| <= 1
            dst[2 * i + 1] = sh;
        }
    }
    if (s >= B) return;

    const v2* xv = reinterpret_cast<const v2*>(x + (size_t)s * NQ);
    const v2 x01 = xv[0], x23 = xv[1], x45 = xv[2];

    const v2* W1v = reinterpret_cast<const v2*>(W1);  // rows of 6 = 3 v2
    const v2* W2v = reinterpret_cast<const v2*>(W2);  // rows of 64 = 32 v2

    v2 xpa[NQ];
#pragma unroll
    for (int i = 0; i < NQ; ++i) xpa[i] = mk2(b2[i], 0.0f);
#pragma unroll
    for (int k2 = 0; k2 < PD / 2; ++k2) {
        float hu[2];
#pragma unroll
        for (int u = 0; u < 2; ++u) {
            const int j = 2 * k2 + u;
            v2 acc = mk2(b1[j], 0.0f);
            acc = pkfma(x01, W1v[j * 3 + 0], acc);
            acc = pkfma(x23, W1v[j * 3 + 1], acc);
            acc = pkfma(x45, W1v[j * 3 + 2], acc);
            hu[u] = fmaxf(acc.x + acc.y, 0.0f);
        }
        const v2 hv = mk2(hu[0], hu[1]);
#pragma unroll
        for (int i = 0; i < NQ; ++i)
            xpa[i] = pkfma(hv, W2v[i * (PD / 2) + k2], xpa[i]);
    }

    float cs[12];
#pragma unroll
    for (int i = 0; i < NQ; ++i) {
        const float xp = fmaxf(xpa[i].x + xpa[i].y, 0.0f);
        float sh, ch;
        __sincosf(0.5f * xp, &sh, &ch);
        cs[2 * i] = ch; cs[2 * i + 1] = sh;
    }
    float4* o = reinterpret_cast<float4*>(ws + 256) + (size_t)s * 3;
#pragma unroll
    for (int i = 0; i < 3; ++i)
        o[i] = make_float4(cs[4 * i], cs[4 * i + 1], cs[4 * i + 2], cs[4 * i + 3]);
}

// ---- kernel 2: circuit + heads, lane-split.
__global__ __launch_bounds__(256) void qpolicy_kernel(
    const float* __restrict__ ws,
    const float* __restrict__ Wp,
    const float* __restrict__ bp,
    const float* __restrict__ Wv,
    const float* __restrict__ bv,
    float* __restrict__ out,
    int B)
{
    const int t = blockIdx.x * blockDim.x + threadIdx.x; // 0 .. 2B-1
    const int s = t >> 1;                                // sample index
    const bool podd = (t & 1) != 0;                      // q0 value of this lane

    // ---- load per-sample (c,s) pairs (pair lanes share 48 B; L2-resident).
    const v2* csv = reinterpret_cast<const v2*>(ws + 256) + (size_t)s * 6;
    v2 cs[6];
#pragma unroll
    for (int q = 0; q < 6; ++q) cs[q] = csv[q];

    // ---- AngleEmbedding: product state, packed tree.
    // Layer-0 CNOT(0,1) folded: on odd lanes (q0=1) the conditional
    // [0..7]<->[8..15] swap of a product state == swapping (c1,s1) here.
    const float g0 = podd ? cs[0].y : cs[0].x;
    const v2 cs1f = podd ? __builtin_shufflevector(cs[1], cs[1], 1, 0) : cs[1];
    const v2 e1 = mk2(g0, g0) * cs1f;
    v2 e2[2], e3[4], e4[8], st[16];
    e2[0] = mk2(e1.x, e1.x) * cs[2];
    e2[1] = mk2(e1.y, e1.y) * cs[2];
#pragma unroll
    for (int k = 0; k < 2; ++k) {
        e3[2 * k]     = mk2(e2[k].x, e2[k].x) * cs[3];
        e3[2 * k + 1] = mk2(e2[k].y, e2[k].y) * cs[3];
    }
#pragma unroll
    for (int k = 0; k < 4; ++k) {
        e4[2 * k]     = mk2(e3[k].x, e3[k].x) * cs[4];
        e4[2 * k + 1] = mk2(e3[k].y, e3[k].y) * cs[4];
    }
#pragma unroll
    for (int k = 0; k < 8; ++k) {
        st[2 * k]     = mk2(e4[k].x, e4[k].x) * cs[5];
        st[2 * k + 1] = mk2(e4[k].y, e4[k].y) * cs[5];
    }

    // ---- 4 layers of [CNOT ring] + [RY(qw[l,i])], constants from ws.
#pragma unroll
    for (int l = 0; l < NL; ++l) {
        const float* cst = ws + l * 16;

        // CNOT(0,1): ctrl = lane parity (q0), tgt = j-bit3 (q1).
        // (layer 0's instance folded into the embedding tree above)
        if (l > 0) {
#pragma unroll
            for (int j = 0; j < 8; ++j) {
                const v2 a = st[j], b = st[j | 8];
                st[j]     = podd ? b : a;
                st[j | 8] = podd ? a : b;
            }
        }
        // CNOT(1,2), (2,3), (3,4): pure register renames.
#pragma unroll
        for (int j = 0; j < 16; ++j)
            if ((j & 8) && !(j & 4)) { v2 tm = st[j]; st[j] = st[j | 4]; st[j | 4] = tm; }
#pragma unroll
        for (int j = 0; j < 16; ++j)
            if ((j & 4) && !(j & 2)) { v2 tm = st[j]; st[j] = st[j | 2]; st[j | 2] = tm; }
#pragma unroll
        for (int j = 0; j < 16; ++j)
            if ((j & 2) && !(j & 1)) { v2 tm = st[j]; st[j] = st[j | 1]; st[j | 1] = tm; }
        // CNOT(4,5): ctrl = j-bit0 (q4), tgt = v2 component swap (rename).
#pragma unroll
        for (int j = 0; j < 16; ++j)
            if (j & 1) st[j] = __builtin_shufflevector(st[j], st[j], 1, 0);

        // Fused CNOT(5,0) + RY(q0), KA/KB form (== round-4 verified step):
        //   st'.x = c*st.x + ssg*dpp(st.x);  st'.y = ssg*st.y + c*dpp(st.y)
        {
            const float c0 = cst[0], s0 = cst[1];
            const float ssg = podd ? s0 : -s0;
            const v2 KA = mk2(c0, ssg);
            const v2 KB = mk2(ssg, c0);
#pragma unroll
            for (int j = 0; j < 16; ++j) {
                const float dx = dppx1(st[j].x);
                const float dy = dppx1(st[j].y);
                st[j] = pkfma(KB, mk2(dx, dy), KA * st[j]);
            }
        }

        // RY(q1..q4): packed 3-shear per register pair (8 pairs each).
#pragma unroll
        for (int i = 1; i <= 4; ++i) {
            const int m = 1 << (4 - i);
            const v2 vnt = mk2(cst[2 * i], cst[2 * i]);          // -tan(h/2)
            const v2 vs  = mk2(cst[2 * i + 1], cst[2 * i + 1]);  // sin(h)
#pragma unroll
            for (int j = 0; j < 16; ++j) {
                if (!(j & m)) {
                    v2 a = st[j], b = st[j | m];
                    a = pkfma(vnt, b, a);
                    b = pkfma(vs, a, b);
                    a = pkfma(vnt, b, a);
                    st[j] = a; st[j | m] = b;
                }
            }
        }
        // RY(q5): packed direct rotation: st' = c*st + (-s,s)*swap(st).
        {
            const float c5 = cst[10], s5 = cst[11];
            const v2 ms  = mk2(-s5, s5);
            const v2 vc5 = mk2(c5, c5);
#pragma unroll
            for (int j = 0; j < 16; ++j) {
                const v2 sw = __builtin_shufflevector(st[j], st[j], 1, 0);
                st[j] = pkfma(ms, sw, st[j] * vc5);
            }
        }
    }

    // ---- probabilities + Z expectations, packed partial-sum tree.
    v2 asq[16];
#pragma unroll
    for (int j = 0; j < 16; ++j) asq[j] = st[j] * st[j];

    v2 s1a = asq[0];
#pragma unroll
    for (int j = 1; j < 8; ++j) s1a += asq[j];         // b3=0 (q1)
    v2 c8[8];
#pragma unroll
    for (int j = 0; j < 8; ++j) c8[j] = asq[j] + asq[j | 8];
    v2 c4[4];
#pragma unroll
    for (int j = 0; j < 4; ++j) c4[j] = c8[j] + c8[j | 4];
    const v2 s2a = (c8[0] + c8[1]) + (c8[2] + c8[3]);  // b2=0 (q2)
    v2 c2[2];
    c2[0] = c4[0] + c4[2];
    c2[1] = c4[1] + c4[3];
    const v2 s3a = c4[0] + c4[1];                      // b1=0 (q3)
    const v2 s4a = c2[0];                              // b0=0 (q4)
    const v2 ta  = c2[0] + c2[1];                      // total

    const float Tl  = ta.x + ta.y;
    const float S5l = ta.x;                            // q5=0 = component x
    const float S1l = s1a.x + s1a.y;
    const float S2l = s2a.x + s2a.y;
    const float S3l = s3a.x + s3a.y;
    const float S4l = s4a.x + s4a.y;

    const float To = dppx1(Tl);
    const float T  = Tl + To;
    const float S0 = podd ? To : Tl;                   // q0 = lane parity
    const float S1 = S1l + dppx1(S1l);
    const float S2 = S2l + dppx1(S2l);
    const float S3 = S3l + dppx1(S3l);
    const float S4 = S4l + dppx1(S4l);
    const float S5 = S5l + dppx1(S5l);

    float z[NQ];
    z[0] = fmaf(2.0f, S0, -T);
    z[1] = fmaf(2.0f, S1, -T);
    z[2] = fmaf(2.0f, S2, -T);
    z[3] = fmaf(2.0f, S3, -T);
    z[4] = fmaf(2.0f, S4, -T);
    z[5] = fmaf(2.0f, S5, -T);

    // ---- heads (computed on both lanes, stored by the even lane only).
    float logits[NA];
#pragma unroll
    for (int aidx = 0; aidx < NA; ++aidx) {
        float acc = bp[aidx];
#pragma unroll
        for (int q = 0; q < NQ; ++q) acc = fmaf(z[q], Wp[aidx * NQ + q], acc);
        logits[aidx] = acc;
    }
    float m = logits[0];
#pragma unroll
    for (int aidx = 1; aidx < NA; ++aidx) m = fmaxf(m, logits[aidx]);
    float e[NA];
    float esum = 0.0f;
#pragma unroll
    for (int aidx = 0; aidx < NA; ++aidx) { e[aidx] = __expf(logits[aidx] - m); esum += e[aidx]; }
    const float inv = 1.0f / esum;

    float4 pol;
    pol.x = e[0] * inv; pol.y = e[1] * inv; pol.z = e[2] * inv; pol.w = e[3] * inv;

    float v = bv[0];
#pragma unroll
    for (int q = 0; q < NQ; ++q) v = fmaf(z[q], Wv[q], v);

    if (!podd) {
        reinterpret_cast<float4*>(out)[s] = pol;       // policy: (B,4)
        out[(size_t)B * NA + s] = v;                   // value: (B,)
    }
}

extern "C" void kernel_launch(void* const* d_in, const int* in_sizes, int n_in,
                              void* d_out, int out_size, void* d_ws, size_t ws_size,
                              hipStream_t stream) {
    const float* x  = (const float*)d_in[0];
    const float* W1 = (const float*)d_in[1];
    const float* b1 = (const float*)d_in[2];
    const float* W2 = (const float*)d_in[3];
    const float* b2 = (const float*)d_in[4];
    const float* qw = (const float*)d_in[5];
    const float* Wp = (const float*)d_in[6];
    const float* bp = (const float*)d_in[7];
    const float* Wv = (const float*)d_in[8];
    const float* bv = (const float*)d_in[9];
    float* out = (float*)d_out;
    float* ws  = (float*)d_ws;   // needs 256 + 12*B floats (~12.6 MB)

    const int B = in_sizes[0] / NQ;      // 262144

    hipLaunchKernelGGL(mlp_kernel, dim3((B + 255) / 256), dim3(256), 0, stream,
                       x, W1, b1, W2, b2, qw, ws, B);

    hipLaunchKernelGGL(qpolicy_kernel, dim3((2 * B + 255) / 256), dim3(256), 0, stream,
                       ws, Wp, bp, Wv, bv, out, B);
}

// Round 7
// 101.366 us; speedup vs baseline: 1.0456x; 1.0456x over previous
//
#include <hip/hip_runtime.h>
#include <math.h>

// QuantumPolicy: MLP(6->64->6) -> 6-qubit RY/CNOT circuit (4 layers) -> Z exp
// -> softmax policy head (4) + value head (1).
//
// ROUND-7: SINGLE FUSED KERNEL (2B threads, 256/block, each block owns 128
// samples) with intra-block phase specialization:
//   Phase 1: threads 0..127 (waves 0-1) run the full per-sample MLP with
//            wave-uniform weight addresses (pure s_load path, zero
//            redundancy) and write (cos,sin)(xp/2) to LDS; threads 128..151
//            (wave 2, otherwise idle) compute the 24 layer rotation constants
//            into LDS -- free overlap. Waves 2-3 wait at the barrier without
//            consuming issue slots.
//   Phase 2: all 256 threads run the LANE-SPLIT circuit (verified round-6
//            body): qubit 0 = lane parity (DPP quad pairs), qubits 1..4 =
//            register index bits, qubit 5 = v2 component; 16 x float2/lane.
// This deletes the round-6 second dispatch, the inter-kernel gap, and the
// ~25 MB ws round-trip (d_ws is now unused).
//
// Circuit body (all independently verified in rounds 4/6):
//  - layer-0 CNOT(0,1) folded into the embedding tree;
//  - CNOT(1,2),(2,3),(3,4),(4,5): compile-time register renames;
//  - fused CNOT(5,0)+RY(q0) in KA/KB DPP form;
//  - RY(q1..q4): packed 3-shear (tan/sin, range-reduced);
//  - RY(q5): packed direct rotation;
//  - packed (v2) embedding + measurement trees.

#define NQ 6
#define NL 4
#define NA 4
#define PD 64

typedef float v2 __attribute__((ext_vector_type(2)));

static __device__ __forceinline__ v2 mk2(float a, float b) { v2 r; r.x = a; r.y = b; return r; }
static __device__ __forceinline__ v2 pkfma(v2 a, v2 b, v2 c) { return __builtin_elementwise_fma(a, b, c); }

// Swap with DPP-quad neighbor (lane ^ 1). Full-rate VALU, exec all-on.
static __device__ __forceinline__ float dppx1(float v) {
    int i = __builtin_bit_cast(int, v);
    i = __builtin_amdgcn_mov_dpp(i, 0xB1, 0xF, 0xF, true); // quad_perm [1,0,3,2]
    return __builtin_bit_cast(float, i);
}

__global__ __launch_bounds__(256) void qpolicy_fused(
    const float* __restrict__ x,
    const float* __restrict__ W1,
    const float* __restrict__ b1,
    const float* __restrict__ W2,
    const float* __restrict__ b2,
    const float* __restrict__ qw,
    const float* __restrict__ Wp,
    const float* __restrict__ bp,
    const float* __restrict__ Wv,
    const float* __restrict__ bv,
    float* __restrict__ out,
    int B)
{
    __shared__ float cst[NL * 16];       // layer consts: c0,s0,nt1,s1..nt4,s4,c5,s5
    __shared__ v2 csh[NQ][128];          // per-sample (cos,sin)(xp/2) per qubit

    const int tid = threadIdx.x;

    // ================= Phase 1 =================
    if (tid < 128) {
        // MLP for sample blockIdx*128 + tid; weight indices are wave-uniform.
        const int s = blockIdx.x * 128 + tid;
        const v2* xv = reinterpret_cast<const v2*>(x + (size_t)s * NQ);
        const v2 x01 = xv[0], x23 = xv[1], x45 = xv[2];

        const v2* W1v = reinterpret_cast<const v2*>(W1);  // rows of 6 = 3 v2
        const v2* W2v = reinterpret_cast<const v2*>(W2);  // rows of 64 = 32 v2

        v2 xpa[NQ];
#pragma unroll
        for (int i = 0; i < NQ; ++i) xpa[i] = mk2(b2[i], 0.0f);
#pragma unroll
        for (int k2 = 0; k2 < PD / 2; ++k2) {
            float hu[2];
#pragma unroll
            for (int u = 0; u < 2; ++u) {
                const int j = 2 * k2 + u;
                v2 acc = mk2(b1[j], 0.0f);
                acc = pkfma(x01, W1v[j * 3 + 0], acc);
                acc = pkfma(x23, W1v[j * 3 + 1], acc);
                acc = pkfma(x45, W1v[j * 3 + 2], acc);
                hu[u] = fmaxf(acc.x + acc.y, 0.0f);
            }
            const v2 hv = mk2(hu[0], hu[1]);
#pragma unroll
            for (int i = 0; i < NQ; ++i)
                xpa[i] = pkfma(hv, W2v[i * (PD / 2) + k2], xpa[i]);
        }
#pragma unroll
        for (int i = 0; i < NQ; ++i) {
            const float xp = fmaxf(xpa[i].x + xpa[i].y, 0.0f);
            float sh, ch;
            __sincosf(0.5f * xp, &sh, &ch);
            csh[i][tid] = mk2(ch, sh);
        }
    } else if (tid < 128 + NL * NQ) {
        // Layer rotation constants (wave 2, lanes 0..23): overlaps the MLP.
        const int k = tid - 128, l = k / NQ, i = k - l * NQ;
        const float hh0 = 0.5f * qw[l * NQ + i];
        float* dst = cst + l * 16;
        if (i == 0) {                      // q0: direct rotation (c,s)
            dst[0] = cosf(hh0);
            dst[1] = sinf(hh0);
        } else if (i == 5) {               // q5: direct rotation (c,s)
            dst[10] = cosf(hh0);
            dst[11] = sinf(hh0);
        } else {                           // q1..q4: shear consts, range-reduced
            const float hh = (hh0 > 1.5707963f) ? (hh0 - 3.14159265358979f) : hh0;
            const float sh = sinf(hh), ch = cosf(hh);
            dst[2 * i]     = -sh / (1.0f + ch);   // -tan(h/2), |t| <= 1
            dst[2 * i + 1] = sh;
        }
    }
    __syncthreads();

    // ================= Phase 2: circuit, lane-split =================
    const int sl = tid >> 1;                 // local sample 0..127
    const int s  = blockIdx.x * 128 + sl;    // global sample
    const bool podd = (tid & 1) != 0;        // q0 value of this lane

    v2 cs[NQ];
#pragma unroll
    for (int q = 0; q < NQ; ++q) cs[q] = csh[q][sl];   // pair-broadcast reads

    // ---- AngleEmbedding: product state, packed tree.
    // Layer-0 CNOT(0,1) folded: on odd lanes (q0=1) the conditional
    // [0..7]<->[8..15] swap of a product state == swapping (c1,s1) here.
    const float g0 = podd ? cs[0].y : cs[0].x;
    const v2 cs1f = podd ? __builtin_shufflevector(cs[1], cs[1], 1, 0) : cs[1];
    const v2 e1 = mk2(g0, g0) * cs1f;
    v2 e2[2], e3[4], e4[8], st[16];
    e2[0] = mk2(e1.x, e1.x) * cs[2];
    e2[1] = mk2(e1.y, e1.y) * cs[2];
#pragma unroll
    for (int k = 0; k < 2; ++k) {
        e3[2 * k]     = mk2(e2[k].x, e2[k].x) * cs[3];
        e3[2 * k + 1] = mk2(e2[k].y, e2[k].y) * cs[3];
    }
#pragma unroll
    for (int k = 0; k < 4; ++k) {
        e4[2 * k]     = mk2(e3[k].x, e3[k].x) * cs[4];
        e4[2 * k + 1] = mk2(e3[k].y, e3[k].y) * cs[4];
    }
#pragma unroll
    for (int k = 0; k < 8; ++k) {
        st[2 * k]     = mk2(e4[k].x, e4[k].x) * cs[5];
        st[2 * k + 1] = mk2(e4[k].y, e4[k].y) * cs[5];
    }

    // ---- 4 layers of [CNOT ring] + [RY(qw[l,i])], constants from LDS.
#pragma unroll
    for (int l = 0; l < NL; ++l) {
        float lc[12];
#pragma unroll
        for (int k = 0; k < 12; ++k) lc[k] = cst[l * 16 + k];

        // CNOT(0,1): ctrl = lane parity (q0), tgt = j-bit3 (q1).
        // (layer 0's instance folded into the embedding tree above)
        if (l > 0) {
#pragma unroll
            for (int j = 0; j < 8; ++j) {
                const v2 a = st[j], b = st[j | 8];
                st[j]     = podd ? b : a;
                st[j | 8] = podd ? a : b;
            }
        }
        // CNOT(1,2), (2,3), (3,4): pure register renames.
#pragma unroll
        for (int j = 0; j < 16; ++j)
            if ((j & 8) && !(j & 4)) { v2 tm = st[j]; st[j] = st[j | 4]; st[j | 4] = tm; }
#pragma unroll
        for (int j = 0; j < 16; ++j)
            if ((j & 4) && !(j & 2)) { v2 tm = st[j]; st[j] = st[j | 2]; st[j | 2] = tm; }
#pragma unroll
        for (int j = 0; j < 16; ++j)
            if ((j & 2) && !(j & 1)) { v2 tm = st[j]; st[j] = st[j | 1]; st[j | 1] = tm; }
        // CNOT(4,5): ctrl = j-bit0 (q4), tgt = v2 component swap (rename).
#pragma unroll
        for (int j = 0; j < 16; ++j)
            if (j & 1) st[j] = __builtin_shufflevector(st[j], st[j], 1, 0);

        // Fused CNOT(5,0) + RY(q0), KA/KB DPP form (round-4/6 verified):
        //   st'.x = c*st.x + ssg*dpp(st.x);  st'.y = ssg*st.y + c*dpp(st.y)
        {
            const float c0 = lc[0], s0 = lc[1];
            const float ssg = podd ? s0 : -s0;
            const v2 KA = mk2(c0, ssg);
            const v2 KB = mk2(ssg, c0);
#pragma unroll
            for (int j = 0; j < 16; ++j) {
                const float dx = dppx1(st[j].x);
                const float dy = dppx1(st[j].y);
                st[j] = pkfma(KB, mk2(dx, dy), KA * st[j]);
            }
        }

        // RY(q1..q4): packed 3-shear per register pair (8 pairs each).
#pragma unroll
        for (int i = 1; i <= 4; ++i) {
            const int m = 1 << (4 - i);
            const v2 vnt = mk2(lc[2 * i], lc[2 * i]);          // -tan(h/2)
            const v2 vs  = mk2(lc[2 * i + 1], lc[2 * i + 1]);  // sin(h)
#pragma unroll
            for (int j = 0; j < 16; ++j) {
                if (!(j & m)) {
                    v2 a = st[j], b = st[j | m];
                    a = pkfma(vnt, b, a);
                    b = pkfma(vs, a, b);
                    a = pkfma(vnt, b, a);
                    st[j] = a; st[j | m] = b;
                }
            }
        }
        // RY(q5): packed direct rotation: st' = c*st + (-s,s)*swap(st).
        {
            const float c5 = lc[10], s5 = lc[11];
            const v2 ms  = mk2(-s5, s5);
            const v2 vc5 = mk2(c5, c5);
#pragma unroll
            for (int j = 0; j < 16; ++j) {
                const v2 sw = __builtin_shufflevector(st[j], st[j], 1, 0);
                st[j] = pkfma(ms, sw, st[j] * vc5);
            }
        }
    }

    // ---- probabilities + Z expectations, packed partial-sum tree.
    v2 asq[16];
#pragma unroll
    for (int j = 0; j < 16; ++j) asq[j] = st[j] * st[j];

    v2 s1a = asq[0];
#pragma unroll
    for (int j = 1; j < 8; ++j) s1a += asq[j];         // b3=0 (q1)
    v2 c8[8];
#pragma unroll
    for (int j = 0; j < 8; ++j) c8[j] = asq[j] + asq[j | 8];
    v2 c4[4];
#pragma unroll
    for (int j = 0; j < 4; ++j) c4[j] = c8[j] + c8[j | 4];
    const v2 s2a = (c8[0] + c8[1]) + (c8[2] + c8[3]);  // b2=0 (q2)
    v2 c2[2];
    c2[0] = c4[0] + c4[2];
    c2[1] = c4[1] + c4[3];
    const v2 s3a = c4[0] + c4[1];                      // b1=0 (q3)
    const v2 s4a = c2[0];                              // b0=0 (q4)
    const v2 ta  = c2[0] + c2[1];                      // total

    const float Tl  = ta.x + ta.y;
    const float S5l = ta.x;                            // q5=0 = component x
    const float S1l = s1a.x + s1a.y;
    const float S2l = s2a.x + s2a.y;
    const float S3l = s3a.x + s3a.y;
    const float S4l = s4a.x + s4a.y;

    const float To = dppx1(Tl);
    const float T  = Tl + To;
    const float S0 = podd ? To : Tl;                   // q0 = lane parity
    const float S1 = S1l + dppx1(S1l);
    const float S2 = S2l + dppx1(S2l);
    const float S3 = S3l + dppx1(S3l);
    const float S4 = S4l + dppx1(S4l);
    const float S5 = S5l + dppx1(S5l);

    float z[NQ];
    z[0] = fmaf(2.0f, S0, -T);
    z[1] = fmaf(2.0f, S1, -T);
    z[2] = fmaf(2.0f, S2, -T);
    z[3] = fmaf(2.0f, S3, -T);
    z[4] = fmaf(2.0f, S4, -T);
    z[5] = fmaf(2.0f, S5, -T);

    // ---- heads (computed on both lanes, stored by the even lane only).
    float logits[NA];
#pragma unroll
    for (int aidx = 0; aidx < NA; ++aidx) {
        float acc = bp[aidx];
#pragma unroll
        for (int q = 0; q < NQ; ++q) acc = fmaf(z[q], Wp[aidx * NQ + q], acc);
        logits[aidx] = acc;
    }
    float m = logits[0];
#pragma unroll
    for (int aidx = 1; aidx < NA; ++aidx) m = fmaxf(m, logits[aidx]);
    float e[NA];
    float esum = 0.0f;
#pragma unroll
    for (int aidx = 0; aidx < NA; ++aidx) { e[aidx] = __expf(logits[aidx] - m); esum += e[aidx]; }
    const float inv = 1.0f / esum;

    float4 pol;
    pol.x = e[0] * inv; pol.y = e[1] * inv; pol.z = e[2] * inv; pol.w = e[3] * inv;

    float v = bv[0];
#pragma unroll
    for (int q = 0; q < NQ; ++q) v = fmaf(z[q], Wv[q], v);

    if (!podd) {
        reinterpret_cast<float4*>(out)[s] = pol;       // policy: (B,4)
        out[(size_t)B * NA + s] = v;                   // value: (B,)
    }
}

extern "C" void kernel_launch(void* const* d_in, const int* in_sizes, int n_in,
                              void* d_out, int out_size, void* d_ws, size_t ws_size,
                              hipStream_t stream) {
    const float* x  = (const float*)d_in[0];
    const float* W1 = (const float*)d_in[1];
    const float* b1 = (const float*)d_in[2];
    const float* W2 = (const float*)d_in[3];
    const float* b2 = (const float*)d_in[4];
    const float* qw = (const float*)d_in[5];
    const float* Wp = (const float*)d_in[6];
    const float* bp = (const float*)d_in[7];
    const float* Wv = (const float*)d_in[8];
    const float* bv = (const float*)d_in[9];
    float* out = (float*)d_out;
    (void)d_ws; (void)ws_size;           // workspace unused

    const int B = in_sizes[0] / NQ;      // 262144

    hipLaunchKernelGGL(qpolicy_fused, dim3((2 * B + 255) / 256), dim3(256), 0, stream,
                       x, W1, b1, W2, b2, qw, Wp, bp, Wv, bv, out, B);
}